// Round 2
// baseline (1245.620 us; speedup 1.0000x reference)
//
#include <hip/hip_runtime.h>

// Synonym: top-5 cosine similarity, 512 queries x 400000x300 fp32 table.
// v3 pipeline (resubmit — round-1 bench was an infra container failure):
//   P0a qprep  : gather+normalize query rows -> qf (fp32) + qsw (bf16,
//                B-fragment-swizzled, K-pad 320)
//   P0b prenorm: table -> row-normalized bf16, swizzled in MFMA A-frag order
//   P1  score  : 256-thr blocks, 4 waves share one 64-query LDS panel (40 KB
//                -> 4 blocks/CU, 16 waves/CU). 8 sibling blocks (same rows,
//                different query octants) pinned to one XCD -> ~1 table pass
//                of L2 fill. Max-gated per-lane top-3, grp-merged to top-6.
//   P2  topk   : scan 3072 cands/query -> top-32 -> exact fp32 rescore -> top-5

#define VOCAB   400000
#define DIM     300
#define NQ      512
#define NT      25000      // 16-row tiles
#define TILE_U  5120       // u16 per swizzled tile (10 ksteps * 512)
#define QFSTR   304        // fp32 query row stride
#define TOPK    5
#define NCAND   3072       // per-query cand slots: 128 rb * 4 wave * 6

using f32x4 = __attribute__((ext_vector_type(4))) float;
using s16x8 = __attribute__((ext_vector_type(8))) short;

__device__ __forceinline__ unsigned short f2bf(float f) {
  unsigned int u = __builtin_bit_cast(unsigned int, f);
  u += 0x7fffu + ((u >> 16) & 1u);   // RNE to bf16
  return (unsigned short)(u >> 16);
}

__device__ __forceinline__ void ins3(float v, int id, float* tv, int* ti) {
  if (v > tv[2]) {
    if (v > tv[0]) {
      tv[2] = tv[1]; ti[2] = ti[1]; tv[1] = tv[0]; ti[1] = ti[0];
      tv[0] = v; ti[0] = id;
    } else if (v > tv[1]) {
      tv[2] = tv[1]; ti[2] = ti[1]; tv[1] = v; ti[1] = id;
    } else {
      tv[2] = v; ti[2] = id;
    }
  }
}

// ---------------- P0a: query gather + normalize ----------------
// qsw layout (B-fragment order): element (q, k=ks*32+grp*8+j) at u16 offset
// (q>>4)*TILE_U + ks*512 + grp*128 + (q&15)*8 + j. A wave's B-frag load for
// (qtile, ks) is qsw + qt*TILE_U + ks*512 + lane*8 : contiguous 1 KB.
__global__ __launch_bounds__(64)
void qprep_kernel(const float* __restrict__ emb, const int* __restrict__ wid,
                  float* __restrict__ qf, unsigned short* __restrict__ qsw) {
  const int q = blockIdx.x;
  const int lane = threadIdx.x;
  const long long w = (long long)wid[q];
  const float* row = emb + w * DIM;
  float x[5];
  double ss = 0.0;
#pragma unroll
  for (int j = 0; j < 5; ++j) {
    const int k = lane + 64 * j;
    x[j] = (k < DIM) ? row[k] : 0.0f;
    ss += (double)x[j] * (double)x[j];
  }
#pragma unroll
  for (int m = 1; m < 64; m <<= 1) ss += __shfl_xor(ss, m, 64);
  const double rinv = 1.0 / sqrt(ss);
#pragma unroll
  for (int j = 0; j < 5; ++j) {
    const int k = lane + 64 * j;
    if (k < DIM) qf[q * QFSTR + k] = (float)((double)x[j] * rinv);
  }
  // swizzled bf16 write: lanes 0..39 each own one (ks,grp) 8-chunk
  if (lane < 40) {
    const int ks = lane >> 2, grp = lane & 3;
    const int k0 = ks * 32 + grp * 8;
    unsigned int pw[4];
#pragma unroll
    for (int h = 0; h < 4; ++h) {
      const int k = k0 + 2 * h;
      float v0 = 0.f, v1 = 0.f;
      if (k < DIM)     v0 = (float)((double)row[k] * rinv);
      if (k + 1 < DIM) v1 = (float)((double)row[k + 1] * rinv);
      pw[h] = (unsigned int)f2bf(v0) | ((unsigned int)f2bf(v1) << 16);
    }
    uint4 pk; pk.x = pw[0]; pk.y = pw[1]; pk.z = pw[2]; pk.w = pw[3];
    *(uint4*)(qsw + (size_t)(q >> 4) * TILE_U + ks * 512 + grp * 128 + (q & 15) * 8) = pk;
  }
}

// ---------------- P0b: table -> normalized bf16, A-frag swizzled ----------------
// Swizzle: tile t (16 rows), element (row=t*16+r, k=ks*32+grp*8+j) lives at
// u16 offset t*5120 + ks*512 + grp*128 + r*8 + j. A wave's A-frag load for
// (tile, ks) is sw + t*5120 + ks*512 + lane*8 : one contiguous 1 KB read.
__global__ __launch_bounds__(256)
void prenorm_kernel(const float* __restrict__ emb, unsigned short* __restrict__ sw) {
  const int wave = threadIdx.x >> 6, lane = threadIdx.x & 63;
  const int t = blockIdx.x * 4 + wave;          // 6250 blocks * 4 = 25000 exact
  const int r = lane & 15, grp = lane >> 4;
  const float* row = emb + (size_t)(t * 16 + r) * DIM;

  float x[10][8];
  float ss = 0.f;
#pragma unroll
  for (int ks = 0; ks < 10; ++ks) {
    const int k0 = ks * 32 + grp * 8;
    if (k0 + 8 <= DIM) {
      const f32x4 u = *(const f32x4*)(row + k0);
      const f32x4 v = *(const f32x4*)(row + k0 + 4);
#pragma unroll
      for (int j = 0; j < 4; ++j) { x[ks][j] = u[j]; x[ks][j + 4] = v[j]; }
    } else {
#pragma unroll
      for (int j = 0; j < 8; ++j) {
        const int k = k0 + j;
        x[ks][j] = (k < DIM) ? row[k] : 0.0f;
      }
    }
#pragma unroll
    for (int j = 0; j < 8; ++j) ss += x[ks][j] * x[ks][j];
  }
  // row sumsq: partners are lanes r, r+16, r+32, r+48
  ss += __shfl_xor(ss, 16, 64);
  ss += __shfl_xor(ss, 32, 64);
  const float rinv = rsqrtf(ss);

  unsigned short* dst = sw + (size_t)t * TILE_U + lane * 8;
#pragma unroll
  for (int ks = 0; ks < 10; ++ks) {
    uint4 pk;
    unsigned int w0 = f2bf(x[ks][0] * rinv) | ((unsigned int)f2bf(x[ks][1] * rinv) << 16);
    unsigned int w1 = f2bf(x[ks][2] * rinv) | ((unsigned int)f2bf(x[ks][3] * rinv) << 16);
    unsigned int w2 = f2bf(x[ks][4] * rinv) | ((unsigned int)f2bf(x[ks][5] * rinv) << 16);
    unsigned int w3 = f2bf(x[ks][6] * rinv) | ((unsigned int)f2bf(x[ks][7] * rinv) << 16);
    pk.x = w0; pk.y = w1; pk.z = w2; pk.w = w3;
    *(uint4*)(dst + ks * 512) = pk;
  }
}

// ---------------- P1: MFMA score + windowed candidates ----------------
// Grid 1024 blocks x 256 threads. bid = xcd + 8*(moct + 8*z):
//   moct = query octant (64 queries), rb = xcd + 8*z = row stripe (0..127).
// The 8 blocks sharing rb (all octants) map to one XCD -> table lines fill
// that L2 once and are reused 8x. All 4 waves of a block share the 64-query
// LDS B-panel (40,960 B -> 4 blocks/CU); wave w covers tiles wt..wt+3 per it.
// 12 full its cover 24576 tiles; tail it=12 runs only for wt<424 (exact).
__global__ __launch_bounds__(256, 4)
void score_kernel(const unsigned short* __restrict__ sw,
                  const unsigned short* __restrict__ qsw,
                  float2* __restrict__ cand) {
  __shared__ __align__(16) unsigned short qlds[4 * TILE_U];   // 40,960 B

  const int tid = threadIdx.x;
  const int wave = tid >> 6, lane = tid & 63;
  const int l15 = lane & 15, grp = lane >> 4;
  const int bid = blockIdx.x;
  const int moct = (bid >> 3) & 7;
  const int rb = (bid & 7) | ((bid >> 6) << 3);   // 0..127

  // stage the 64-query B-panel (4 q-tiles) once
  {
    const uint4* src = (const uint4*)(qsw + (size_t)moct * 4 * TILE_U);
    uint4* dst = (uint4*)qlds;
#pragma unroll
    for (int i = 0; i < 10; ++i) dst[tid + 256 * i] = src[tid + 256 * i];
  }
  __syncthreads();

  float v3[4][3]; int i3[4][3];
#pragma unroll
  for (int qi = 0; qi < 4; ++qi)
#pragma unroll
    for (int j = 0; j < 3; ++j) { v3[qi][j] = -1e30f; i3[qi][j] = 0; }

  const unsigned short* bq = qlds + lane * 8;
  const int wt = rb * 16 + wave * 4;              // wave's tile offset in stripe
  const int nit = (wt < 424) ? 13 : 12;           // 24576 + 424 = 25000 exact

  for (int it = 0; it < nit; ++it) {
    const int t0 = it * 2048 + wt;
    const unsigned short* ap = sw + (size_t)t0 * TILE_U + lane * 8;

    f32x4 acc[4][4];
#pragma unroll
    for (int qi = 0; qi < 4; ++qi)
#pragma unroll
      for (int vi = 0; vi < 4; ++vi) acc[qi][vi] = {0.f, 0.f, 0.f, 0.f};

#pragma unroll
    for (int ks = 0; ks < 10; ++ks) {
      s16x8 a[4];
#pragma unroll
      for (int vi = 0; vi < 4; ++vi)
        a[vi] = *(const s16x8*)(ap + (size_t)vi * TILE_U + ks * 512);
#pragma unroll
      for (int qi = 0; qi < 4; ++qi) {
        const s16x8 b = *(const s16x8*)(bq + qi * TILE_U + ks * 512);
#pragma unroll
        for (int vi = 0; vi < 4; ++vi)
          acc[qi][vi] = __builtin_amdgcn_mfma_f32_16x16x32_bf16(a[vi], b, acc[qi][vi], 0, 0, 0);
      }
    }

    // scan acc -> per-lane top-3, gated by 4-wide max
    // (C/D layout: row = tile*16 + grp*4 + rr, col = query l15)
#pragma unroll
    for (int vi = 0; vi < 4; ++vi) {
      const int rbase = (t0 + vi) * 16 + grp * 4;
#pragma unroll
      for (int qi = 0; qi < 4; ++qi) {
        const f32x4 a4 = acc[qi][vi];
        const float m01 = fmaxf(a4[0], a4[1]);
        const float m23 = fmaxf(a4[2], a4[3]);
        if (fmaxf(m01, m23) > v3[qi][2]) {
#pragma unroll
          for (int rr = 0; rr < 4; ++rr)
            ins3(a4[rr], rbase + rr, &v3[qi][0], &i3[qi][0]);
        }
      }
    }
  }

  // merge 4 grp-lanes' top-3 -> union top-6 (>=5, so no probabilistic loss
  // at this stage), write 6 cand slots per (query, rb, wave)
#pragma unroll
  for (int qi = 0; qi < 4; ++qi) {
    float m0 = v3[qi][0], m1 = v3[qi][1], m2 = v3[qi][2];
    int   d0 = i3[qi][0], d1 = i3[qi][1], d2 = i3[qi][2];
    const int q = moct * 64 + qi * 16 + l15;
    float2* dst = cand + (size_t)q * NCAND + (rb * 24 + wave * 6);
#pragma unroll
    for (int r = 0; r < 6; ++r) {
      float bv = m0; int bi = d0; int bl = grp;
      float ov = __shfl_xor(bv, 16, 64);
      int   oi = __shfl_xor(bi, 16, 64);
      int   ol = __shfl_xor(bl, 16, 64);
      if (ov > bv || (ov == bv && ol < bl)) { bv = ov; bi = oi; bl = ol; }
      ov = __shfl_xor(bv, 32, 64);
      oi = __shfl_xor(bi, 32, 64);
      ol = __shfl_xor(bl, 32, 64);
      if (ov > bv || (ov == bv && ol < bl)) { bv = ov; bi = oi; bl = ol; }
      if (bl == grp) { m0 = m1; d0 = d1; m1 = m2; d1 = d2; m2 = -1e30f; }
      if (r == grp || r == grp + 4) {
        float2 e; e.x = bv; e.y = __int_as_float(bi);
        dst[r] = e;
      }
    }
  }
}

// ---------------- P2: merge candidates, exact rescore, top-5 ----------------
__global__ __launch_bounds__(256)
void topk_kernel(const float* __restrict__ emb, const float* __restrict__ qf,
                 const float2* __restrict__ cand, float* __restrict__ out) {
  __shared__ float pV[256 * 6];
  __shared__ int   pI[256 * 6];
  __shared__ int   selI[32];
  __shared__ float resV[32];

  const int q = blockIdx.x;
  const int t = threadIdx.x;
  const float2* cq = cand + (size_t)q * NCAND;

  // per-thread top-6 over 3072/256 = 12 entries
  float bv[6]; int bi[6];
#pragma unroll
  for (int j = 0; j < 6; ++j) { bv[j] = -1e30f; bi[j] = -1; }
  for (int i = t; i < NCAND; i += 256) {
    const float2 e = cq[i];
    const float v = e.x;
    if (v > bv[5]) {
      bv[5] = v; bi[5] = __float_as_int(e.y);
#pragma unroll
      for (int j = 5; j > 0; --j) {
        if (bv[j] > bv[j - 1]) {
          const float tv2 = bv[j]; bv[j] = bv[j - 1]; bv[j - 1] = tv2;
          const int ti2 = bi[j]; bi[j] = bi[j - 1]; bi[j - 1] = ti2;
        }
      }
    }
  }
#pragma unroll
  for (int j = 0; j < 6; ++j) { pV[t * 6 + j] = bv[j]; pI[t * 6 + j] = bi[j]; }
  __syncthreads();

  // wave 0: select top-32 (approx values) from the 1536-entry pool
  if (t < 64) {
    for (int r = 0; r < 32; ++r) {
      float mv = -2e30f; int mp = 0;
      for (int i = t; i < 256 * 6; i += 64) {
        const float v = pV[i];
        if (v > mv) { mv = v; mp = i; }
      }
#pragma unroll
      for (int m = 1; m < 64; m <<= 1) {
        const float ov = __shfl_xor(mv, m, 64);
        const int   op = __shfl_xor(mp, m, 64);
        if (ov > mv) { mv = ov; mp = op; }
      }
      if (t == 0) { selI[r] = pI[mp]; pV[mp] = -2e30f; }
      __builtin_amdgcn_wave_barrier();
    }
  }
  __syncthreads();

  // exact fp32 rescore of 32 candidates, 8 threads each
  {
    const int j = t >> 3, sub = t & 7;
    const int id = selI[j];
    float dot = 0.f, sq = 0.f;
    if (id >= 0) {
      const f32x4* e4 = (const f32x4*)(emb + (size_t)id * DIM);
      const f32x4* q4 = (const f32x4*)(qf + (size_t)q * QFSTR);
      for (int f = sub; f < DIM / 4; f += 8) {
        const f32x4 ev = e4[f], qv = q4[f];
        dot += ev[0]*qv[0] + ev[1]*qv[1] + ev[2]*qv[2] + ev[3]*qv[3];
        sq  += ev[0]*ev[0] + ev[1]*ev[1] + ev[2]*ev[2] + ev[3]*ev[3];
      }
    }
#pragma unroll
    for (int m = 1; m < 8; m <<= 1) {
      dot += __shfl_xor(dot, m, 64);
      sq  += __shfl_xor(sq, m, 64);
    }
    if (sub == 0)
      resV[j] = (id >= 0 && sq > 0.f) ? (float)((double)dot / sqrt((double)sq)) : -2e30f;
  }
  __syncthreads();

  if (t == 0) {
#pragma unroll
    for (int r = 0; r < TOPK; ++r) {
      float mv = -3e30f; int mp = 0;
      for (int i = 0; i < 32; ++i) if (resV[i] > mv) { mv = resV[i]; mp = i; }
      out[q * TOPK + r] = mv;
      out[NQ * TOPK + q * TOPK + r] = (float)selI[mp];
      resV[mp] = -3e30f;
    }
  }
}

extern "C" void kernel_launch(void* const* d_in, const int* in_sizes, int n_in,
                              void* d_out, int out_size, void* d_ws, size_t ws_size,
                              hipStream_t stream) {
  (void)in_sizes; (void)n_in; (void)out_size; (void)ws_size;
  const float* emb = (const float*)d_in[0];
  const int* wid = (const int*)d_in[1];   // word_ids; d_in[2] (k=5) hardcoded
  float* out = (float*)d_out;

  // workspace layout (total 269,533,184 B <= previous 269,541,376):
  //   qsw  @ 0         : 32*5120*2   =    327,680
  //   qf   @ 327680    : 512*304*4   =    622,592
  //   cand @ 950272    : 512*3072*8  = 12,582,912
  //   sw   @ 13533184  : 25000*10240 = 256,000,000
  char* ws = (char*)d_ws;
  unsigned short* qsw = (unsigned short*)ws;
  float*  qf   = (float*)(ws + 327680);
  float2* cand = (float2*)(ws + 950272);
  unsigned short* sw = (unsigned short*)(ws + 13533184);

  qprep_kernel<<<NQ, 64, 0, stream>>>(emb, wid, qf, qsw);
  prenorm_kernel<<<NT / 4, 256, 0, stream>>>(emb, sw);
  score_kernel<<<1024, 256, 0, stream>>>(sw, qsw, cand);
  topk_kernel<<<NQ, 256, 0, stream>>>(emb, qf, cand, out);
}